// Round 6
// baseline (468.197 us; speedup 1.0000x reference)
//
#include <hip/hip_runtime.h>
#include <hip/hip_bf16.h>

// Problem constants (fixed by the reference)
constexpr int N_NODES = 50000;
constexpr int N_EDGES = 800000;
constexpr int R_REL   = 8;
constexpr int BASES   = 4;
constexpr int D       = 256;                 // DIN = DH = DOUT
constexpr int KZ      = BASES * D;           // 1024: basis-space aggregate
constexpr int KT      = KZ + D;              // 1280: + self block
constexpr int WSTRIDE = 16;                  // wtab float4s per node
constexpr int DUMMY_P = 8 << 20;             // dummy edge: src=0, rel=8

// Sort geometry: coarse bucket = 256 consecutive dst nodes.
constexpr int NHI    = (N_NODES + 255) / 256;   // 196 coarse buckets
constexpr int NS_BLK = 200;                     // coarse-pass blocks
constexpr int CH     = N_EDGES / NS_BLK;        // 4000 edges/block (exact)

// grid geometry
constexpr int NB  = (N_NODES + 255) / 256;        // 196
constexpr int CB4 = (N_NODES * 128) / 1024;       // 6250 (exact; 4 uints/thread)
constexpr int WKB = KT / 64;                      // 20 (make_w blocks per layer)
constexpr int WB  = (N_NODES * WSTRIDE) / 256;    // 3125 (exact)
constexpr int CAP = N_EDGES + N_NODES * 8;        // 1,200,000 padded edge cap
constexpr int FB4 = (CAP + 1023) / 1024;          // 1172 (4 ints/thread)
constexpr int WF4 = (CAP + 1023) / 1024;          // 1172 (4 float4/thread)

typedef __attribute__((ext_vector_type(8))) short bf16x8;
typedef __attribute__((ext_vector_type(4))) float f32x4;

__device__ inline float bfu_lo(unsigned u) { return __uint_as_float(u << 16); }
__device__ inline float bfu_hi(unsigned u) { return __uint_as_float(u & 0xFFFF0000u); }
__device__ inline unsigned short f2bu(float f) {
  __hip_bfloat16 h = __float2bfloat16(f);
  return *reinterpret_cast<unsigned short*>(&h);
}
__device__ inline void store_out(float* p, float v) { *p = v; }
__device__ inline void store_out(__hip_bfloat16* p, float v) { *p = __float2bfloat16(v); }

// async 16B global -> LDS (wave-uniform lds base + lane*16)
__device__ inline void gload_lds16(void* lds, const void* g) {
  __builtin_amdgcn_global_load_lds(
      (const __attribute__((address_space(1))) unsigned*)g,
      (__attribute__((address_space(3))) unsigned*)lds, 16, 0, 0);
}

// ---------------------------------------------------------------------------
// 1. Fused prep: [coarse-hist P1 | convert | make_w x2 | fill packed/wedge]
// ---------------------------------------------------------------------------
__global__ __launch_bounds__(256) void prep_kernel(
    const int* __restrict__ ei, const int* __restrict__ et,
    int* __restrict__ gcoarse,
    const float* __restrict__ x, unsigned* __restrict__ x2,
    const float* __restrict__ basis1, const float* __restrict__ root1,
    __hip_bfloat16* __restrict__ WT1,
    const float* __restrict__ basis2, const float* __restrict__ root2,
    __hip_bfloat16* __restrict__ WT2,
    int* __restrict__ packed,
    float4* __restrict__ wedge1, float4* __restrict__ wedge2) {
  __shared__ __hip_bfloat16 tile[16][256];   // 8 KB (make_w)
  __shared__ int hist[NHI];                  // (P1)
  int bid = blockIdx.x;
  int tid = threadIdx.x;

  if (bid < NS_BLK) {                   // --- P1: coarse histogram ---
    if (tid < NHI) hist[tid] = 0;
    __syncthreads();
    int start = bid * CH, end = start + CH;
    for (int i = start + tid; i < end; i += 256) {
      int dst = ei[N_EDGES + i];
      atomicAdd(&hist[dst >> 8], 1);    // LDS atomic
    }
    __syncthreads();
    if (tid < NHI && hist[tid] > 0) atomicAdd(&gcoarse[tid], hist[tid]);
    return;
  }
  bid -= NS_BLK;
  if (bid < CB4) {                      // --- convert x -> bf16 (4 uints/thr) ---
    int idx = (bid * 256 + tid) * 4;    // exact: CB4*1024 == N*128
    const float* px = x + (size_t)idx * 2;
    float4 a = *(const float4*)(px);
    float4 b = *(const float4*)(px + 4);
    uint4 o;
    o.x = (unsigned)f2bu(a.x) | ((unsigned)f2bu(a.y) << 16);
    o.y = (unsigned)f2bu(a.z) | ((unsigned)f2bu(a.w) << 16);
    o.z = (unsigned)f2bu(b.x) | ((unsigned)f2bu(b.y) << 16);
    o.w = (unsigned)f2bu(b.z) | ((unsigned)f2bu(b.w) << 16);
    *(uint4*)(x2 + idx) = o;
    return;
  }
  bid -= CB4;
  if (bid < 2 * WKB) {                  // --- weight build (both layers) ---
    const float* basis = (bid < WKB) ? basis1 : basis2;
    const float* root  = (bid < WKB) ? root1 : root2;
    __hip_bfloat16* WT = (bid < WKB) ? WT1 : WT2;
    int wb = (bid < WKB) ? bid : bid - WKB;
    int k0 = wb * 64;
#pragma unroll
    for (int pass = 0; pass < 4; pass++) {
      int kp = k0 + pass * 16;
#pragma unroll
      for (int r = 0; r < 16; r++) {
        int k = kp + r;
        const float* srow = (k < KZ)
            ? basis + ((size_t)(k & 3) * D + (k >> 2)) * D
            : root + (size_t)(k - KZ) * D;
        tile[r][tid] = __float2bfloat16(srow[tid]);
      }
      __syncthreads();
      __hip_bfloat16* dst = WT + (size_t)tid * KT + kp;
#pragma unroll
      for (int c = 0; c < 2; c++) {
        union { short s[8]; int4 v; } u;
#pragma unroll
        for (int r = 0; r < 8; r++)
          u.s[r] = *reinterpret_cast<short*>(&tile[c * 8 + r][tid]);
        *(int4*)(dst + c * 8) = u.v;
      }
      __syncthreads();
    }
    return;
  }
  bid -= 2 * WKB;
  if (bid < FB4) {                      // --- dummy-fill packed (4 ints/thr) ---
    int i = (bid * 256 + tid) * 4;
    if (i < CAP) {                      // CAP % 4 == 0 -> full int4 valid
      int4 f = make_int4(DUMMY_P, DUMMY_P, DUMMY_P, DUMMY_P);
      *(int4*)(packed + i) = f;
    }
    return;
  }
  bid -= FB4;
  {                                     // --- zero-fill wedge (4 f4/thr) ---
    float4* wz = (bid < WF4) ? wedge1 : wedge2;
    int lb = (bid < WF4) ? bid : bid - WF4;
    int i = (lb * 256 + tid) * 4;
    if (i < CAP) {
      float4 z = make_float4(0.f, 0.f, 0.f, 0.f);
      wz[i] = z; wz[i + 1] = z; wz[i + 2] = z; wz[i + 3] = z;
    }
  }
}

// ---------------------------------------------------------------------------
// 2. P2: exclusive prefix of coarse counts -> gbase; init running cursors.
// ---------------------------------------------------------------------------
__global__ __launch_bounds__(256) void coarse_prefix_kernel(
    const int* __restrict__ gcoarse, int* __restrict__ gbase,
    int* __restrict__ gcur) {
  __shared__ int sd[256];
  int tid = threadIdx.x;
  int v = (tid < NHI) ? gcoarse[tid] : 0;
  sd[tid] = v;
  __syncthreads();
  for (int off = 1; off < 256; off <<= 1) {
    int t = (tid >= off) ? sd[tid - off] : 0;
    __syncthreads();
    sd[tid] += t;
    __syncthreads();
  }
  if (tid < NHI) {
    int b = sd[tid] - v;
    gbase[tid] = b;
    gcur[tid] = b;
  }
}

// ---------------------------------------------------------------------------
// 3. P3: coarse scatter. Per-block LDS hist -> one range-claim atomic per
//    bin -> scatter edges as 27-bit words src | rt<<16 | (dst&255)<<19.
// ---------------------------------------------------------------------------
__global__ __launch_bounds__(256) void coarse_scatter_kernel(
    const int* __restrict__ ei, const int* __restrict__ et,
    int* __restrict__ gcur, int* __restrict__ coarse) {
  __shared__ int hist[NHI];
  __shared__ int lbase[NHI];
  __shared__ int lcnt[NHI];
  int bid = blockIdx.x;
  int tid = threadIdx.x;
  if (tid < NHI) { hist[tid] = 0; lcnt[tid] = 0; }
  __syncthreads();
  int start = bid * CH, end = start + CH;
  for (int i = start + tid; i < end; i += 256)
    atomicAdd(&hist[ei[N_EDGES + i] >> 8], 1);
  __syncthreads();
  if (tid < NHI) lbase[tid] = atomicAdd(&gcur[tid], hist[tid]);
  __syncthreads();
  for (int i = start + tid; i < end; i += 256) {
    int src = ei[i];
    int dst = ei[N_EDGES + i];
    int rt  = et[i];
    int bin = dst >> 8;
    int rank = atomicAdd(&lcnt[bin], 1);   // LDS atomic
    coarse[lbase[bin] + rank] = src | (rt << 16) | ((dst & 255) << 19);
  }
}

// ---------------------------------------------------------------------------
// 4. P4a: per coarse bucket: fine hist over 256x8 keys (LDS), write cnt,
//    padded per-node degrees + local exclusive prefix, bucket total.
// ---------------------------------------------------------------------------
__global__ __launch_bounds__(256) void fine_hist_kernel(
    const int* __restrict__ coarse, const int* __restrict__ gbase,
    const int* __restrict__ gcoarse, int* __restrict__ cnt,
    int* __restrict__ lestart, int* __restrict__ btot) {
  __shared__ int c2[256 * R_REL];   // 8 KB fine histogram
  __shared__ int sd[256];
  int b = blockIdx.x;
  int tid = threadIdx.x;
#pragma unroll
  for (int k = tid; k < 256 * R_REL; k += 256) c2[k] = 0;
  __syncthreads();
  int base = gbase[b], n_e = gcoarse[b];
  for (int i = tid; i < n_e; i += 256) {
    int e = coarse[base + i];
    int key = ((e >> 19) & 255) * R_REL + ((e >> 16) & 7);
    atomicAdd(&c2[key], 1);
  }
  __syncthreads();
  // write cnt for winv
  int nodebase = b * 256;
#pragma unroll
  for (int k = tid; k < 256 * R_REL; k += 256) {
    int n = nodebase + (k >> 3);
    if (n < N_NODES) cnt[n * R_REL + (k & 7)] = c2[k];
  }
  // padded degree + prefix (thread tid owns node nodebase+tid)
  int d = 0;
#pragma unroll
  for (int r = 0; r < R_REL; r++) d += c2[tid * R_REL + r];
  int dp = (d + 7) & ~7;
  sd[tid] = dp;
  __syncthreads();
  for (int off = 1; off < 256; off <<= 1) {
    int t = (tid >= off) ? sd[tid - off] : 0;
    __syncthreads();
    sd[tid] += t;
    __syncthreads();
  }
  lestart[b * 256 + tid] = sd[tid] - dp;
  if (tid == 255) btot[b] = sd[255];
}

// ---------------------------------------------------------------------------
// 5. P4b: prefix of per-bucket padded totals -> bbase; estart[N] = total.
// ---------------------------------------------------------------------------
__global__ __launch_bounds__(256) void btot_prefix_kernel(
    const int* __restrict__ btot, int* __restrict__ bbase,
    int* __restrict__ estart) {
  __shared__ int sd[256];
  int tid = threadIdx.x;
  int v = (tid < NHI) ? btot[tid] : 0;
  sd[tid] = v;
  __syncthreads();
  for (int off = 1; off < 256; off <<= 1) {
    int t = (tid >= off) ? sd[tid - off] : 0;
    __syncthreads();
    sd[tid] += t;
    __syncthreads();
  }
  if (tid < NHI) bbase[tid] = sd[tid] - v;
  if (tid == NHI - 1) estart[N_NODES] = sd[tid];
}

// ---------------------------------------------------------------------------
// 6. P4c fused with winv: estart[n] = bbase[n>>8] + lestart[n]; wtab build.
// ---------------------------------------------------------------------------
__global__ __launch_bounds__(256) void finalize_kernel(
    const int* __restrict__ bbase, const int* __restrict__ lestart,
    int* __restrict__ estart, const int* __restrict__ cnt,
    const float* __restrict__ comp1, float4* __restrict__ wtab1,
    const float* __restrict__ comp2, float4* __restrict__ wtab2) {
  int bid = blockIdx.x;
  int tid = threadIdx.x;
  if (bid < NB) {                       // --- estart ---
    int n = bid * 256 + tid;
    if (n < N_NODES) estart[n] = bbase[n >> 8] + lestart[n];
    return;
  }
  bid -= NB;
  {                                     // --- winv (both layers) ---
    const float* comp = (bid < WB) ? comp1 : comp2;
    float4* wtab = (bid < WB) ? wtab1 : wtab2;
    int lb = (bid < WB) ? bid : bid - WB;
    int idx = lb * 256 + tid;           // exact: WB*256 == N*WSTRIDE
    int r = idx & (WSTRIDE - 1);
    int n = idx >> 4;
    float4 w = make_float4(0.f, 0.f, 0.f, 0.f);
    if (r < R_REL) {
      int c = cnt[n * R_REL + r];
      float inv = 1.0f / (float)(c > 0 ? c : 1);
      w.x = comp[r * BASES + 0] * inv;
      w.y = comp[r * BASES + 1] * inv;
      w.z = comp[r * BASES + 2] * inv;
      w.w = comp[r * BASES + 3] * inv;
    }
    wtab[idx] = w;
  }
}

// ---------------------------------------------------------------------------
// 7. P5: final scatter into padded packed layout (LDS rank counters; pad
//    slots keep DUMMY_P / zero wedge). Also materializes the per-edge
//    weight streams wedge1/wedge2 so the aggregate inner loop has NO
//    data-dependent scalar loads (round-6 change).
// ---------------------------------------------------------------------------
__global__ __launch_bounds__(256) void fine_scatter_kernel(
    const int* __restrict__ coarse, const int* __restrict__ gbase,
    const int* __restrict__ gcoarse, const int* __restrict__ bbase,
    const int* __restrict__ lestart,
    const float4* __restrict__ wtab1, const float4* __restrict__ wtab2,
    int* __restrict__ packed,
    float4* __restrict__ wedge1, float4* __restrict__ wedge2) {
  __shared__ int lest[256];
  __shared__ int lcur[256];
  int b = blockIdx.x;
  int tid = threadIdx.x;
  lest[tid] = lestart[b * 256 + tid];
  lcur[tid] = 0;
  __syncthreads();
  int base = gbase[b], n_e = gcoarse[b];
  int sb = bbase[b];
  for (int i = tid; i < n_e; i += 256) {
    int e = coarse[base + i];
    int lo = (e >> 19) & 255;
    int rt = (e >> 16) & 7;
    int rank = atomicAdd(&lcur[lo], 1);   // LDS atomic
    int pos = sb + lest[lo] + rank;
    packed[pos] = (e & 0xFFFF) | (rt << 20);
    int widx = (b * 256 + lo) * WSTRIDE + rt;
    wedge1[pos] = wtab1[widx];
    wedge2[pos] = wtab2[widx];
  }
}

// ---------------------------------------------------------------------------
// 8. Aggregate into basis space. WAVE per node (4/block). Scalar pipe does
//    all wave-uniform work. Round-6: weights come from the SEQUENTIAL
//    per-edge wedge stream (induction-variable address, pipelinable)
//    instead of a wtab lookup dependent on the packed value -- the only
//    data-dependent load left is the x2 gather itself.
// ---------------------------------------------------------------------------
__device__ inline float2 pfma(float s, float2 a, float2 c) {
  c.x = fmaf(s, a.x, c.x);
  c.y = fmaf(s, a.y, c.y);
  return c;
}

__device__ inline void edge_fma(float2 acc[BASES][2], uint2 v, float4 w) {
  float2 a01 = make_float2(bfu_lo(v.x), bfu_hi(v.x));
  float2 a23 = make_float2(bfu_lo(v.y), bfu_hi(v.y));
  acc[0][0] = pfma(w.x, a01, acc[0][0]); acc[0][1] = pfma(w.x, a23, acc[0][1]);
  acc[1][0] = pfma(w.y, a01, acc[1][0]); acc[1][1] = pfma(w.y, a23, acc[1][1]);
  acc[2][0] = pfma(w.z, a01, acc[2][0]); acc[2][1] = pfma(w.z, a23, acc[2][1]);
  acc[3][0] = pfma(w.w, a01, acc[3][0]); acc[3][1] = pfma(w.w, a23, acc[3][1]);
}

__global__ __launch_bounds__(256) void aggregate_kernel(
    const unsigned* __restrict__ x2,   // bf16 features as uint pairs [N][128]
    const int* __restrict__ packed,    // padded-x8 buckets
    const float4* __restrict__ wedge,  // per-edge weights (pads = 0)
    const int* __restrict__ estart,    // padded offsets
    __hip_bfloat16* __restrict__ zA)   // [N][KZ]
{
  int tid = threadIdx.x;
  int lane = tid & 63;
  int n = __builtin_amdgcn_readfirstlane(blockIdx.x * 4 + (tid >> 6));
  int s = __builtin_amdgcn_readfirstlane(estart[n]);
  int e = __builtin_amdgcn_readfirstlane(estart[n + 1]);
  const int voff = lane * 2;                         // uint index within row

  float2 acc[BASES][2] = {};

  for (int base = s; base < e; base += 8) {
    int4 q0 = *(const int4*)(packed + base);         // uniform addr -> s_load
    int4 q1 = *(const int4*)(packed + base + 4);
    int p0 = __builtin_amdgcn_readfirstlane(q0.x);
    int p1 = __builtin_amdgcn_readfirstlane(q0.y);
    int p2 = __builtin_amdgcn_readfirstlane(q0.z);
    int p3 = __builtin_amdgcn_readfirstlane(q0.w);
    int p4 = __builtin_amdgcn_readfirstlane(q1.x);
    int p5 = __builtin_amdgcn_readfirstlane(q1.y);
    int p6 = __builtin_amdgcn_readfirstlane(q1.z);
    int p7 = __builtin_amdgcn_readfirstlane(q1.w);
    // SGPR row bases; vector part is just base+voff
    const unsigned* r0 = x2 + ((size_t)(p0 & 0xFFFFF) << 7);
    const unsigned* r1 = x2 + ((size_t)(p1 & 0xFFFFF) << 7);
    const unsigned* r2 = x2 + ((size_t)(p2 & 0xFFFFF) << 7);
    const unsigned* r3 = x2 + ((size_t)(p3 & 0xFFFFF) << 7);
    const unsigned* r4 = x2 + ((size_t)(p4 & 0xFFFFF) << 7);
    const unsigned* r5 = x2 + ((size_t)(p5 & 0xFFFFF) << 7);
    const unsigned* r6 = x2 + ((size_t)(p6 & 0xFFFFF) << 7);
    const unsigned* r7 = x2 + ((size_t)(p7 & 0xFFFFF) << 7);
    uint2 v0 = *(const uint2*)(r0 + voff);
    uint2 v1 = *(const uint2*)(r1 + voff);
    uint2 v2 = *(const uint2*)(r2 + voff);
    uint2 v3 = *(const uint2*)(r3 + voff);
    uint2 v4 = *(const uint2*)(r4 + voff);
    uint2 v5 = *(const uint2*)(r5 + voff);
    uint2 v6 = *(const uint2*)(r6 + voff);
    uint2 v7 = *(const uint2*)(r7 + voff);
    // sequential weight stream: addresses independent of packed values
    float4 w0 = wedge[base + 0];
    float4 w1 = wedge[base + 1];
    float4 w2 = wedge[base + 2];
    float4 w3 = wedge[base + 3];
    float4 w4 = wedge[base + 4];
    float4 w5 = wedge[base + 5];
    float4 w6 = wedge[base + 6];
    float4 w7 = wedge[base + 7];
    edge_fma(acc, v0, w0);
    edge_fma(acc, v1, w1);
    edge_fma(acc, v2, w2);
    edge_fma(acc, v3, w3);
    edge_fma(acc, v4, w4);
    edge_fma(acc, v5, w5);
    edge_fma(acc, v6, w6);
    edge_fma(acc, v7, w7);
  }

  // store: k = (4*lane+j)*4 + b = 16*lane + 4*j + b -> 32 contiguous bytes
  union { short s[8]; int4 v; } u0, u1;
#pragma unroll
  for (int b = 0; b < BASES; b++) {
    u0.s[b]     = (short)f2bu(acc[b][0].x);
    u0.s[4 + b] = (short)f2bu(acc[b][0].y);
    u1.s[b]     = (short)f2bu(acc[b][1].x);
    u1.s[4 + b] = (short)f2bu(acc[b][1].y);
  }
  __hip_bfloat16* zrow = zA + (size_t)n * KZ;
  *(int4*)(zrow + 16 * lane) = u0.v;
  *(int4*)(zrow + 16 * lane + 8) = u1.v;
}

// ---------------------------------------------------------------------------
// 9. GEMM: C[M,256] = A[M,1280](bf16) @ WT^T + bias. BM=128, BN=256, 512
//    threads / 8 waves, BK=32. Round-6: 2-phase double-buffered staging --
//    raw s_barrier + counted vmcnt(3) keeps the next tile's 3
//    global_load_lds in flight across the barrier while MFMA runs
//    (previous __syncthreads drained vmcnt to 0 every step = no overlap).
// ---------------------------------------------------------------------------
#define BM 128
#define BN 256
#define BK 32

template <bool RELU, typename OutT>
__global__ __launch_bounds__(512) void gemm_kernel(
    const __hip_bfloat16* __restrict__ Az,     // [M, KZ]
    const __hip_bfloat16* __restrict__ Aself,  // [M, D]
    const __hip_bfloat16* __restrict__ Bt,     // [256, KT]
    const float* __restrict__ bias, OutT* __restrict__ C, int M) {
  __shared__ __align__(16) __hip_bfloat16 As[2][BM * BK];  // 2 x 8 KB
  __shared__ __align__(16) __hip_bfloat16 Bs[2][BN * BK];  // 2 x 16 KB
  int tid = threadIdx.x;
  int m0 = blockIdx.x * BM;
  int wave = tid >> 6, lane = tid & 63;
  int wm = wave & 1, wn = wave >> 1;   // 2 x 4 wave grid, 64x64 tiles
  int l15 = lane & 15, quad = lane >> 4;

  int colS = (lane & 3) * 8;
  int rowA = wave * 16 + (lane >> 2);           // 0..127 across 8 waves
  int grA  = min(m0 + rowA, M - 1);             // clamp; epilogue masks tail
  const __hip_bfloat16* gAz = Az + (size_t)grA * KZ + colS;
  const __hip_bfloat16* gAs = Aself + (size_t)grA * D + colS;
  const __hip_bfloat16* gB0 = Bt + (size_t)(wave * 32 + (lane >> 2)) * KT + colS;
  const __hip_bfloat16* gB1 = gB0 + 16 * KT;

  f32x4 acc[4][4] = {};

  auto stage = [&](int buf, int k0) {
    const __hip_bfloat16* srcA = (k0 < KZ) ? (gAz + k0) : (gAs + (k0 - KZ));
    gload_lds16(As[buf] + wave * 512, srcA);
    gload_lds16(Bs[buf] + wave * 1024, gB0 + k0);
    gload_lds16(Bs[buf] + wave * 1024 + 512, gB1 + k0);
  };

  stage(0, 0);
  int cur = 0;
  for (int k0 = 0; k0 < KT; k0 += BK) {
    if (k0 + BK < KT) {
      stage(cur ^ 1, k0 + BK);                      // prefetch next tile
      asm volatile("s_waitcnt vmcnt(3)" ::: "memory");  // cur's 3 loads done
    } else {
      asm volatile("s_waitcnt vmcnt(0)" ::: "memory");  // tail: drain all
    }
    __builtin_amdgcn_s_barrier();
    __builtin_amdgcn_sched_barrier(0);

    bf16x8 af[4], bfr[4];
#pragma unroll
    for (int mt = 0; mt < 4; mt++)
      af[mt] = *(const bf16x8*)(As[cur] + (wm * 64 + mt * 16 + l15) * BK + quad * 8);
#pragma unroll
    for (int nt = 0; nt < 4; nt++)
      bfr[nt] = *(const bf16x8*)(Bs[cur] + (wn * 64 + nt * 16 + l15) * BK + quad * 8);
#pragma unroll
    for (int mt = 0; mt < 4; mt++)
#pragma unroll
      for (int nt = 0; nt < 4; nt++)
        acc[mt][nt] = __builtin_amdgcn_mfma_f32_16x16x32_bf16(
            af[mt], bfr[nt], acc[mt][nt], 0, 0, 0);
    __builtin_amdgcn_s_barrier();   // all reads of buf cur retired (lgkm
                                    // drained before MFMA by compiler)
    cur ^= 1;
  }

  // epilogue: C/D layout col = lane&15, row = quad*4 + reg
#pragma unroll
  for (int nt = 0; nt < 4; nt++) {
    int cg = wn * 64 + nt * 16 + l15;
    float bv = bias[cg];
#pragma unroll
    for (int mt = 0; mt < 4; mt++) {
#pragma unroll
      for (int r = 0; r < 4; r++) {
        int rg = m0 + wm * 64 + mt * 16 + quad * 4 + r;
        if (rg < M) {
          float v = acc[mt][nt][r] + bv;
          if (RELU) v = fmaxf(v, 0.f);
          store_out(C + (size_t)rg * D + cg, v);
        }
      }
    }
  }
}

// ---------------------------------------------------------------------------
// Launch
// ---------------------------------------------------------------------------
static inline char* carve(char*& p, size_t bytes) {
  char* r = p;
  p += (bytes + 255) & ~(size_t)255;
  return r;
}

extern "C" void kernel_launch(void* const* d_in, const int* in_sizes, int n_in,
                              void* d_out, int out_size, void* d_ws,
                              size_t ws_size, hipStream_t stream) {
  const float* x      = (const float*)d_in[0];
  const int*   ei     = (const int*)d_in[1];
  const int*   et     = (const int*)d_in[2];
  const float* basis1 = (const float*)d_in[3];
  const float* comp1  = (const float*)d_in[4];
  const float* root1  = (const float*)d_in[5];
  const float* bias1  = (const float*)d_in[6];
  const float* basis2 = (const float*)d_in[7];
  const float* comp2  = (const float*)d_in[8];
  const float* root2  = (const float*)d_in[9];
  const float* bias2  = (const float*)d_in[10];
  float* out = (float*)d_out;

  char* ws = (char*)d_ws;
  int* cnt     = (int*)carve(ws, (size_t)N_NODES * R_REL * 4);
  int* estart  = (int*)carve(ws, (size_t)(N_NODES + 1) * 4);
  int* coarse  = (int*)carve(ws, (size_t)N_EDGES * 4);
  int* lestart = (int*)carve(ws, (size_t)NHI * 256 * 4);
  int* gcoarse = (int*)carve(ws, 256 * 4);
  int* gbase   = (int*)carve(ws, 256 * 4);
  int* gcur    = (int*)carve(ws, 256 * 4);
  int* btot    = (int*)carve(ws, 256 * 4);
  int* bbase   = (int*)carve(ws, 256 * 4);
  int* packed  = (int*)carve(ws, (size_t)CAP * 4);
  float4* wedge1 = (float4*)carve(ws, (size_t)CAP * 16);
  float4* wedge2 = (float4*)carve(ws, (size_t)CAP * 16);
  float4* wtab1 = (float4*)carve(ws, (size_t)N_NODES * WSTRIDE * 16);
  float4* wtab2 = (float4*)carve(ws, (size_t)N_NODES * WSTRIDE * 16);
  __hip_bfloat16* WT1 = (__hip_bfloat16*)carve(ws, (size_t)D * KT * 2);
  __hip_bfloat16* WT2 = (__hip_bfloat16*)carve(ws, (size_t)D * KT * 2);
  unsigned* xb = (unsigned*)carve(ws, (size_t)N_NODES * D * 2);   // bf16 x
  __hip_bfloat16* h = (__hip_bfloat16*)carve(ws, (size_t)N_NODES * D * 2);
  __hip_bfloat16* zA = (__hip_bfloat16*)carve(ws, (size_t)N_NODES * KZ * 2);

  hipMemsetAsync(gcoarse, 0, 256 * 4, stream);

  prep_kernel<<<NS_BLK + CB4 + 2 * WKB + FB4 + 2 * WF4, 256, 0, stream>>>(
      ei, et, gcoarse, x, xb, basis1, root1, WT1, basis2, root2, WT2,
      packed, wedge1, wedge2);
  coarse_prefix_kernel<<<1, 256, 0, stream>>>(gcoarse, gbase, gcur);
  coarse_scatter_kernel<<<NS_BLK, 256, 0, stream>>>(ei, et, gcur, coarse);
  fine_hist_kernel<<<NHI, 256, 0, stream>>>(coarse, gbase, gcoarse, cnt,
                                            lestart, btot);
  btot_prefix_kernel<<<1, 256, 0, stream>>>(btot, bbase, estart);
  finalize_kernel<<<NB + 2 * WB, 256, 0, stream>>>(bbase, lestart, estart, cnt,
                                                   comp1, wtab1, comp2, wtab2);
  fine_scatter_kernel<<<NHI, 256, 0, stream>>>(coarse, gbase, gcoarse, bbase,
                                               lestart, wtab1, wtab2,
                                               packed, wedge1, wedge2);

  dim3 ggrid((N_NODES + BM - 1) / BM, 1);  // 391 blocks, full N per block
  const int AB = (N_NODES + 3) / 4;        // 12500 blocks, wave per node

  // Layer 1
  aggregate_kernel<<<AB, 256, 0, stream>>>(xb, packed, wedge1, estart, zA);
  gemm_kernel<true, __hip_bfloat16><<<ggrid, 512, 0, stream>>>(
      zA, (const __hip_bfloat16*)xb, WT1, bias1, h, N_NODES);

  // Layer 2 (h is bf16 [N][256] — same packed-uint view as xb)
  aggregate_kernel<<<AB, 256, 0, stream>>>((const unsigned*)h, packed, wedge2,
                                           estart, zA);
  gemm_kernel<false, float><<<ggrid, 512, 0, stream>>>(
      zA, h, WT2, bias2, out, N_NODES);
}

// Round 7
// 441.649 us; speedup vs baseline: 1.0601x; 1.0601x over previous
//
#include <hip/hip_runtime.h>
#include <hip/hip_bf16.h>

// Problem constants (fixed by the reference)
constexpr int N_NODES = 50000;
constexpr int N_EDGES = 800000;
constexpr int R_REL   = 8;
constexpr int BASES   = 4;
constexpr int D       = 256;                 // DIN = DH = DOUT
constexpr int KZ      = BASES * D;           // 1024: basis-space aggregate
constexpr int KT      = KZ + D;              // 1280: + self block
constexpr int WSTRIDE = 16;                  // wtab float4s per node (slots 8..15
                                             // are zero -> dummy edges)
constexpr int DUMMY_P = 8 << 20;             // dummy edge: src=0, rel=8

// Sort geometry: coarse bucket = 256 consecutive dst nodes.
constexpr int NHI    = (N_NODES + 255) / 256;   // 196 coarse buckets
constexpr int NS_BLK = 200;                     // coarse-pass blocks
constexpr int CH     = N_EDGES / NS_BLK;        // 4000 edges/block (exact)

// grid geometry
constexpr int CB4 = (N_NODES * 128) / 1024;       // 6250 (exact; 4 uints/thread)
constexpr int WKB = KT / 64;                      // 20 (make_w blocks per layer)
constexpr int CAP = N_EDGES + N_NODES * 8;        // 1,200,000 padded edge cap
constexpr int FB4 = (CAP + 1023) / 1024;          // 1172 (4 ints/thread)

typedef __attribute__((ext_vector_type(8))) short bf16x8;
typedef __attribute__((ext_vector_type(4))) float f32x4;

__device__ inline float bfu_lo(unsigned u) { return __uint_as_float(u << 16); }
__device__ inline float bfu_hi(unsigned u) { return __uint_as_float(u & 0xFFFF0000u); }
__device__ inline unsigned short f2bu(float f) {
  __hip_bfloat16 h = __float2bfloat16(f);
  return *reinterpret_cast<unsigned short*>(&h);
}
__device__ inline void store_out(float* p, float v) { *p = v; }
__device__ inline void store_out(__hip_bfloat16* p, float v) { *p = __float2bfloat16(v); }

// async 16B global -> LDS (wave-uniform lds base + lane*16)
__device__ inline void gload_lds16(void* lds, const void* g) {
  __builtin_amdgcn_global_load_lds(
      (const __attribute__((address_space(1))) unsigned*)g,
      (__attribute__((address_space(3))) unsigned*)lds, 16, 0, 0);
}

// ---------------------------------------------------------------------------
// 1. Fused prep: [coarse-hist P1 | convert | make_w x2 | dummy-fill packed]
// ---------------------------------------------------------------------------
__global__ __launch_bounds__(256) void prep_kernel(
    const int* __restrict__ ei, const int* __restrict__ et,
    int* __restrict__ gcoarse,
    const float* __restrict__ x, unsigned* __restrict__ x2,
    const float* __restrict__ basis1, const float* __restrict__ root1,
    __hip_bfloat16* __restrict__ WT1,
    const float* __restrict__ basis2, const float* __restrict__ root2,
    __hip_bfloat16* __restrict__ WT2,
    int* __restrict__ packed) {
  __shared__ __hip_bfloat16 tile[16][256];   // 8 KB (make_w)
  __shared__ int hist[NHI];                  // (P1)
  int bid = blockIdx.x;
  int tid = threadIdx.x;

  if (bid < NS_BLK) {                   // --- P1: coarse histogram ---
    if (tid < NHI) hist[tid] = 0;
    __syncthreads();
    int start = bid * CH, end = start + CH;
    for (int i = start + tid; i < end; i += 256) {
      int dst = ei[N_EDGES + i];
      atomicAdd(&hist[dst >> 8], 1);    // LDS atomic
    }
    __syncthreads();
    if (tid < NHI && hist[tid] > 0) atomicAdd(&gcoarse[tid], hist[tid]);
    return;
  }
  bid -= NS_BLK;
  if (bid < CB4) {                      // --- convert x -> bf16 (4 uints/thr) ---
    int idx = (bid * 256 + tid) * 4;    // exact: CB4*1024 == N*128
    const float* px = x + (size_t)idx * 2;
    float4 a = *(const float4*)(px);
    float4 b = *(const float4*)(px + 4);
    uint4 o;
    o.x = (unsigned)f2bu(a.x) | ((unsigned)f2bu(a.y) << 16);
    o.y = (unsigned)f2bu(a.z) | ((unsigned)f2bu(a.w) << 16);
    o.z = (unsigned)f2bu(b.x) | ((unsigned)f2bu(b.y) << 16);
    o.w = (unsigned)f2bu(b.z) | ((unsigned)f2bu(b.w) << 16);
    *(uint4*)(x2 + idx) = o;
    return;
  }
  bid -= CB4;
  if (bid < 2 * WKB) {                  // --- weight build (both layers) ---
    const float* basis = (bid < WKB) ? basis1 : basis2;
    const float* root  = (bid < WKB) ? root1 : root2;
    __hip_bfloat16* WT = (bid < WKB) ? WT1 : WT2;
    int wb = (bid < WKB) ? bid : bid - WKB;
    int k0 = wb * 64;
#pragma unroll
    for (int pass = 0; pass < 4; pass++) {
      int kp = k0 + pass * 16;
#pragma unroll
      for (int r = 0; r < 16; r++) {
        int k = kp + r;
        const float* srow = (k < KZ)
            ? basis + ((size_t)(k & 3) * D + (k >> 2)) * D
            : root + (size_t)(k - KZ) * D;
        tile[r][tid] = __float2bfloat16(srow[tid]);
      }
      __syncthreads();
      __hip_bfloat16* dst = WT + (size_t)tid * KT + kp;
#pragma unroll
      for (int c = 0; c < 2; c++) {
        union { short s[8]; int4 v; } u;
#pragma unroll
        for (int r = 0; r < 8; r++)
          u.s[r] = *reinterpret_cast<short*>(&tile[c * 8 + r][tid]);
        *(int4*)(dst + c * 8) = u.v;
      }
      __syncthreads();
    }
    return;
  }
  bid -= 2 * WKB;
  {                                     // --- dummy-fill packed (4 ints/thr) ---
    int i = (bid * 256 + tid) * 4;
    if (i < CAP) {                      // CAP % 4 == 0 -> full int4 valid
      int4 f = make_int4(DUMMY_P, DUMMY_P, DUMMY_P, DUMMY_P);
      *(int4*)(packed + i) = f;
    }
  }
}

// ---------------------------------------------------------------------------
// 2. P2: exclusive prefix of coarse counts -> gbase; init running cursors.
// ---------------------------------------------------------------------------
__global__ __launch_bounds__(256) void coarse_prefix_kernel(
    const int* __restrict__ gcoarse, int* __restrict__ gbase,
    int* __restrict__ gcur) {
  __shared__ int sd[256];
  int tid = threadIdx.x;
  int v = (tid < NHI) ? gcoarse[tid] : 0;
  sd[tid] = v;
  __syncthreads();
  for (int off = 1; off < 256; off <<= 1) {
    int t = (tid >= off) ? sd[tid - off] : 0;
    __syncthreads();
    sd[tid] += t;
    __syncthreads();
  }
  if (tid < NHI) {
    int b = sd[tid] - v;
    gbase[tid] = b;
    gcur[tid] = b;
  }
}

// ---------------------------------------------------------------------------
// 3. P3: coarse scatter. Per-block LDS hist -> one range-claim atomic per
//    bin -> scatter edges as 27-bit words src | rt<<16 | (dst&255)<<19.
// ---------------------------------------------------------------------------
__global__ __launch_bounds__(256) void coarse_scatter_kernel(
    const int* __restrict__ ei, const int* __restrict__ et,
    int* __restrict__ gcur, int* __restrict__ coarse) {
  __shared__ int hist[NHI];
  __shared__ int lbase[NHI];
  __shared__ int lcnt[NHI];
  int bid = blockIdx.x;
  int tid = threadIdx.x;
  if (tid < NHI) { hist[tid] = 0; lcnt[tid] = 0; }
  __syncthreads();
  int start = bid * CH, end = start + CH;
  for (int i = start + tid; i < end; i += 256)
    atomicAdd(&hist[ei[N_EDGES + i] >> 8], 1);
  __syncthreads();
  if (tid < NHI) lbase[tid] = atomicAdd(&gcur[tid], hist[tid]);
  __syncthreads();
  for (int i = start + tid; i < end; i += 256) {
    int src = ei[i];
    int dst = ei[N_EDGES + i];
    int rt  = et[i];
    int bin = dst >> 8;
    int rank = atomicAdd(&lcnt[bin], 1);   // LDS atomic
    coarse[lbase[bin] + rank] = src | (rt << 16) | ((dst & 255) << 19);
  }
}

// ---------------------------------------------------------------------------
// 4. P4a: per coarse bucket: fine hist over 256x8 keys (LDS); from the
//    in-LDS histogram directly build wtab1/wtab2 (winv fused here -- the
//    global cnt array and the separate finalize/winv kernel are gone);
//    write padded per-node local prefix + bucket total.
// ---------------------------------------------------------------------------
__global__ __launch_bounds__(256) void fine_hist_kernel(
    const int* __restrict__ coarse, const int* __restrict__ gbase,
    const int* __restrict__ gcoarse,
    const float* __restrict__ comp1, float4* __restrict__ wtab1,
    const float* __restrict__ comp2, float4* __restrict__ wtab2,
    int* __restrict__ lestart, int* __restrict__ btot) {
  __shared__ int c2[256 * R_REL];   // 8 KB fine histogram
  __shared__ int sd[256];
  int b = blockIdx.x;
  int tid = threadIdx.x;
#pragma unroll
  for (int k = tid; k < 256 * R_REL; k += 256) c2[k] = 0;
  __syncthreads();
  int base = gbase[b], n_e = gcoarse[b];
  for (int i = tid; i < n_e; i += 256) {
    int e = coarse[base + i];
    int key = ((e >> 19) & 255) * R_REL + ((e >> 16) & 7);
    atomicAdd(&c2[key], 1);
  }
  __syncthreads();
  // winv (both layers) straight from the LDS histogram
  int nodebase = b * 256;
  for (int k = tid; k < 256 * WSTRIDE; k += 256) {
    int lo = k >> 4, r = k & (WSTRIDE - 1);
    int n = nodebase + lo;
    if (n < N_NODES) {
      float4 w1 = make_float4(0.f, 0.f, 0.f, 0.f);
      float4 w2 = w1;
      if (r < R_REL) {
        int c = c2[lo * R_REL + r];
        float inv = 1.0f / (float)(c > 0 ? c : 1);
        w1.x = comp1[r * BASES + 0] * inv;
        w1.y = comp1[r * BASES + 1] * inv;
        w1.z = comp1[r * BASES + 2] * inv;
        w1.w = comp1[r * BASES + 3] * inv;
        w2.x = comp2[r * BASES + 0] * inv;
        w2.y = comp2[r * BASES + 1] * inv;
        w2.z = comp2[r * BASES + 2] * inv;
        w2.w = comp2[r * BASES + 3] * inv;
      }
      wtab1[(size_t)n * WSTRIDE + r] = w1;
      wtab2[(size_t)n * WSTRIDE + r] = w2;
    }
  }
  // padded degree + prefix (thread tid owns node nodebase+tid)
  int d = 0;
#pragma unroll
  for (int r = 0; r < R_REL; r++) d += c2[tid * R_REL + r];
  int dp = (d + 7) & ~7;
  sd[tid] = dp;
  __syncthreads();
  for (int off = 1; off < 256; off <<= 1) {
    int t = (tid >= off) ? sd[tid - off] : 0;
    __syncthreads();
    sd[tid] += t;
    __syncthreads();
  }
  lestart[b * 256 + tid] = sd[tid] - dp;
  if (tid == 255) btot[b] = sd[255];
}

// ---------------------------------------------------------------------------
// 5. P4b: prefix of per-bucket padded totals -> bbase; estart[N] = total.
// ---------------------------------------------------------------------------
__global__ __launch_bounds__(256) void btot_prefix_kernel(
    const int* __restrict__ btot, int* __restrict__ bbase,
    int* __restrict__ estart) {
  __shared__ int sd[256];
  int tid = threadIdx.x;
  int v = (tid < NHI) ? btot[tid] : 0;
  sd[tid] = v;
  __syncthreads();
  for (int off = 1; off < 256; off <<= 1) {
    int t = (tid >= off) ? sd[tid - off] : 0;
    __syncthreads();
    sd[tid] += t;
    __syncthreads();
  }
  if (tid < NHI) bbase[tid] = sd[tid] - v;
  if (tid == NHI - 1) estart[N_NODES] = sd[tid];
}

// ---------------------------------------------------------------------------
// 6. P5: final scatter into padded packed layout (LDS rank counters; pad
//    slots keep DUMMY_P). Also writes estart (= bbase[b] + local prefix).
// ---------------------------------------------------------------------------
__global__ __launch_bounds__(256) void fine_scatter_kernel(
    const int* __restrict__ coarse, const int* __restrict__ gbase,
    const int* __restrict__ gcoarse, const int* __restrict__ bbase,
    const int* __restrict__ lestart, int* __restrict__ estart,
    int* __restrict__ packed) {
  __shared__ int lest[256];
  __shared__ int lcur[256];
  int b = blockIdx.x;
  int tid = threadIdx.x;
  int sb = bbase[b];
  lest[tid] = lestart[b * 256 + tid];
  lcur[tid] = 0;
  {
    int n = b * 256 + tid;
    if (n < N_NODES) estart[n] = sb + lest[tid];
  }
  __syncthreads();
  int base = gbase[b], n_e = gcoarse[b];
  for (int i = tid; i < n_e; i += 256) {
    int e = coarse[base + i];
    int lo = (e >> 19) & 255;
    int rank = atomicAdd(&lcur[lo], 1);   // LDS atomic
    packed[sb + lest[lo] + rank] = (e & 0xFFFF) | (((e >> 16) & 7) << 20);
  }
}

// ---------------------------------------------------------------------------
// 7. Aggregate into basis space. WAVE per node (4/block). All wave-uniform
//    work (edge list, weights, row bases) on the SCALAR pipe via
//    readfirstlane; buckets padded to x8 -> branch/mask-free inner loop.
//    (R6's per-edge weight stream was NULL -> reverted to wtab s_loads.)
//    Aggregate is at its transport floor: FETCH ~191MB = 8 XCDs x 25.6MB
//    compulsory x2 reads (random src), WRITE 100MB = zA.
// ---------------------------------------------------------------------------
__device__ inline float2 pfma(float s, float2 a, float2 c) {
  c.x = fmaf(s, a.x, c.x);
  c.y = fmaf(s, a.y, c.y);
  return c;
}

__device__ inline void edge_fma(float2 acc[BASES][2], uint2 v, float4 w) {
  float2 a01 = make_float2(bfu_lo(v.x), bfu_hi(v.x));
  float2 a23 = make_float2(bfu_lo(v.y), bfu_hi(v.y));
  acc[0][0] = pfma(w.x, a01, acc[0][0]); acc[0][1] = pfma(w.x, a23, acc[0][1]);
  acc[1][0] = pfma(w.y, a01, acc[1][0]); acc[1][1] = pfma(w.y, a23, acc[1][1]);
  acc[2][0] = pfma(w.z, a01, acc[2][0]); acc[2][1] = pfma(w.z, a23, acc[2][1]);
  acc[3][0] = pfma(w.w, a01, acc[3][0]); acc[3][1] = pfma(w.w, a23, acc[3][1]);
}

__global__ __launch_bounds__(256) void aggregate_kernel(
    const unsigned* __restrict__ x2,   // bf16 features as uint pairs [N][128]
    const int* __restrict__ packed,    // padded-x8 buckets
    const int* __restrict__ estart,    // padded offsets
    const float4* __restrict__ wtab,   // [N*16]; slots 8..15 zero (dummy)
    __hip_bfloat16* __restrict__ zA)   // [N][KZ]
{
  int tid = threadIdx.x;
  int lane = tid & 63;
  int n = __builtin_amdgcn_readfirstlane(blockIdx.x * 4 + (tid >> 6));
  int s = __builtin_amdgcn_readfirstlane(estart[n]);
  int e = __builtin_amdgcn_readfirstlane(estart[n + 1]);
  const int voff = lane * 2;                         // uint index within row
  const float4* wt = wtab + (size_t)n * WSTRIDE;

  float2 acc[BASES][2] = {};

  for (int base = s; base < e; base += 8) {
    int4 q0 = *(const int4*)(packed + base);         // uniform addr -> s_load
    int4 q1 = *(const int4*)(packed + base + 4);
    int p0 = __builtin_amdgcn_readfirstlane(q0.x);
    int p1 = __builtin_amdgcn_readfirstlane(q0.y);
    int p2 = __builtin_amdgcn_readfirstlane(q0.z);
    int p3 = __builtin_amdgcn_readfirstlane(q0.w);
    int p4 = __builtin_amdgcn_readfirstlane(q1.x);
    int p5 = __builtin_amdgcn_readfirstlane(q1.y);
    int p6 = __builtin_amdgcn_readfirstlane(q1.z);
    int p7 = __builtin_amdgcn_readfirstlane(q1.w);
    // SGPR row bases; vector part is just base+voff
    const unsigned* r0 = x2 + ((size_t)(p0 & 0xFFFFF) << 7);
    const unsigned* r1 = x2 + ((size_t)(p1 & 0xFFFFF) << 7);
    const unsigned* r2 = x2 + ((size_t)(p2 & 0xFFFFF) << 7);
    const unsigned* r3 = x2 + ((size_t)(p3 & 0xFFFFF) << 7);
    const unsigned* r4 = x2 + ((size_t)(p4 & 0xFFFFF) << 7);
    const unsigned* r5 = x2 + ((size_t)(p5 & 0xFFFFF) << 7);
    const unsigned* r6 = x2 + ((size_t)(p6 & 0xFFFFF) << 7);
    const unsigned* r7 = x2 + ((size_t)(p7 & 0xFFFFF) << 7);
    uint2 v0 = *(const uint2*)(r0 + voff);
    uint2 v1 = *(const uint2*)(r1 + voff);
    uint2 v2 = *(const uint2*)(r2 + voff);
    uint2 v3 = *(const uint2*)(r3 + voff);
    uint2 v4 = *(const uint2*)(r4 + voff);
    uint2 v5 = *(const uint2*)(r5 + voff);
    uint2 v6 = *(const uint2*)(r6 + voff);
    uint2 v7 = *(const uint2*)(r7 + voff);
    float4 w0 = wt[p0 >> 20];                        // uniform -> s_load_x4
    float4 w1 = wt[p1 >> 20];
    float4 w2 = wt[p2 >> 20];
    float4 w3 = wt[p3 >> 20];
    float4 w4 = wt[p4 >> 20];
    float4 w5 = wt[p5 >> 20];
    float4 w6 = wt[p6 >> 20];
    float4 w7 = wt[p7 >> 20];
    edge_fma(acc, v0, w0);
    edge_fma(acc, v1, w1);
    edge_fma(acc, v2, w2);
    edge_fma(acc, v3, w3);
    edge_fma(acc, v4, w4);
    edge_fma(acc, v5, w5);
    edge_fma(acc, v6, w6);
    edge_fma(acc, v7, w7);
  }

  // store: k = (4*lane+j)*4 + b = 16*lane + 4*j + b -> 32 contiguous bytes
  union { short s[8]; int4 v; } u0, u1;
#pragma unroll
  for (int b = 0; b < BASES; b++) {
    u0.s[b]     = (short)f2bu(acc[b][0].x);
    u0.s[4 + b] = (short)f2bu(acc[b][0].y);
    u1.s[b]     = (short)f2bu(acc[b][1].x);
    u1.s[4 + b] = (short)f2bu(acc[b][1].y);
  }
  __hip_bfloat16* zrow = zA + (size_t)n * KZ;
  *(int4*)(zrow + 16 * lane) = u0.v;
  *(int4*)(zrow + 16 * lane + 8) = u1.v;
}

// ---------------------------------------------------------------------------
// 8. GEMM: C[M,256] = A[M,1280](bf16) @ WT^T + bias. BM=128, BN=256, 512
//    threads / 8 waves, BK=32. 2-phase double-buffered staging: raw
//    s_barrier + counted vmcnt(3) keeps next tile's loads in flight while
//    MFMA runs. A split: k<1024 from Az, k>=1024 from Aself (xb/h).
// ---------------------------------------------------------------------------
#define BM 128
#define BN 256
#define BK 32

template <bool RELU, typename OutT>
__global__ __launch_bounds__(512) void gemm_kernel(
    const __hip_bfloat16* __restrict__ Az,     // [M, KZ]
    const __hip_bfloat16* __restrict__ Aself,  // [M, D]
    const __hip_bfloat16* __restrict__ Bt,     // [256, KT]
    const float* __restrict__ bias, OutT* __restrict__ C, int M) {
  __shared__ __align__(16) __hip_bfloat16 As[2][BM * BK];  // 2 x 8 KB
  __shared__ __align__(16) __hip_bfloat16 Bs[2][BN * BK];  // 2 x 16 KB
  int tid = threadIdx.x;
  int m0 = blockIdx.x * BM;
  int wave = tid >> 6, lane = tid & 63;
  int wm = wave & 1, wn = wave >> 1;   // 2 x 4 wave grid, 64x64 tiles
  int l15 = lane & 15, quad = lane >> 4;

  int colS = (lane & 3) * 8;
  int rowA = wave * 16 + (lane >> 2);           // 0..127 across 8 waves
  int grA  = min(m0 + rowA, M - 1);             // clamp; epilogue masks tail
  const __hip_bfloat16* gAz = Az + (size_t)grA * KZ + colS;
  const __hip_bfloat16* gAs = Aself + (size_t)grA * D + colS;
  const __hip_bfloat16* gB0 = Bt + (size_t)(wave * 32 + (lane >> 2)) * KT + colS;
  const __hip_bfloat16* gB1 = gB0 + 16 * KT;

  f32x4 acc[4][4] = {};

  auto stage = [&](int buf, int k0) {
    const __hip_bfloat16* srcA = (k0 < KZ) ? (gAz + k0) : (gAs + (k0 - KZ));
    gload_lds16(As[buf] + wave * 512, srcA);
    gload_lds16(Bs[buf] + wave * 1024, gB0 + k0);
    gload_lds16(Bs[buf] + wave * 1024 + 512, gB1 + k0);
  };

  stage(0, 0);
  int cur = 0;
  for (int k0 = 0; k0 < KT; k0 += BK) {
    if (k0 + BK < KT) {
      stage(cur ^ 1, k0 + BK);                      // prefetch next tile
      asm volatile("s_waitcnt vmcnt(3)" ::: "memory");  // cur's 3 loads done
    } else {
      asm volatile("s_waitcnt vmcnt(0)" ::: "memory");  // tail: drain all
    }
    __builtin_amdgcn_s_barrier();
    __builtin_amdgcn_sched_barrier(0);

    bf16x8 af[4], bfr[4];
#pragma unroll
    for (int mt = 0; mt < 4; mt++)
      af[mt] = *(const bf16x8*)(As[cur] + (wm * 64 + mt * 16 + l15) * BK + quad * 8);
#pragma unroll
    for (int nt = 0; nt < 4; nt++)
      bfr[nt] = *(const bf16x8*)(Bs[cur] + (wn * 64 + nt * 16 + l15) * BK + quad * 8);
#pragma unroll
    for (int mt = 0; mt < 4; mt++)
#pragma unroll
      for (int nt = 0; nt < 4; nt++)
        acc[mt][nt] = __builtin_amdgcn_mfma_f32_16x16x32_bf16(
            af[mt], bfr[nt], acc[mt][nt], 0, 0, 0);
    __builtin_amdgcn_s_barrier();   // all reads of buf cur retired
    cur ^= 1;
  }

  // epilogue: C/D layout col = lane&15, row = quad*4 + reg
#pragma unroll
  for (int nt = 0; nt < 4; nt++) {
    int cg = wn * 64 + nt * 16 + l15;
    float bv = bias[cg];
#pragma unroll
    for (int mt = 0; mt < 4; mt++) {
#pragma unroll
      for (int r = 0; r < 4; r++) {
        int rg = m0 + wm * 64 + mt * 16 + quad * 4 + r;
        if (rg < M) {
          float v = acc[mt][nt][r] + bv;
          if (RELU) v = fmaxf(v, 0.f);
          store_out(C + (size_t)rg * D + cg, v);
        }
      }
    }
  }
}

// ---------------------------------------------------------------------------
// Launch
// ---------------------------------------------------------------------------
static inline char* carve(char*& p, size_t bytes) {
  char* r = p;
  p += (bytes + 255) & ~(size_t)255;
  return r;
}

extern "C" void kernel_launch(void* const* d_in, const int* in_sizes, int n_in,
                              void* d_out, int out_size, void* d_ws,
                              size_t ws_size, hipStream_t stream) {
  const float* x      = (const float*)d_in[0];
  const int*   ei     = (const int*)d_in[1];
  const int*   et     = (const int*)d_in[2];
  const float* basis1 = (const float*)d_in[3];
  const float* comp1  = (const float*)d_in[4];
  const float* root1  = (const float*)d_in[5];
  const float* bias1  = (const float*)d_in[6];
  const float* basis2 = (const float*)d_in[7];
  const float* comp2  = (const float*)d_in[8];
  const float* root2  = (const float*)d_in[9];
  const float* bias2  = (const float*)d_in[10];
  float* out = (float*)d_out;

  char* ws = (char*)d_ws;
  int* estart  = (int*)carve(ws, (size_t)(N_NODES + 1) * 4);
  int* coarse  = (int*)carve(ws, (size_t)N_EDGES * 4);
  int* lestart = (int*)carve(ws, (size_t)NHI * 256 * 4);
  int* gcoarse = (int*)carve(ws, 256 * 4);
  int* gbase   = (int*)carve(ws, 256 * 4);
  int* gcur    = (int*)carve(ws, 256 * 4);
  int* btot    = (int*)carve(ws, 256 * 4);
  int* bbase   = (int*)carve(ws, 256 * 4);
  int* packed  = (int*)carve(ws, (size_t)CAP * 4);
  float4* wtab1 = (float4*)carve(ws, (size_t)N_NODES * WSTRIDE * 16);
  float4* wtab2 = (float4*)carve(ws, (size_t)N_NODES * WSTRIDE * 16);
  __hip_bfloat16* WT1 = (__hip_bfloat16*)carve(ws, (size_t)D * KT * 2);
  __hip_bfloat16* WT2 = (__hip_bfloat16*)carve(ws, (size_t)D * KT * 2);
  unsigned* xb = (unsigned*)carve(ws, (size_t)N_NODES * D * 2);   // bf16 x
  __hip_bfloat16* h = (__hip_bfloat16*)carve(ws, (size_t)N_NODES * D * 2);
  __hip_bfloat16* zA = (__hip_bfloat16*)carve(ws, (size_t)N_NODES * KZ * 2);

  hipMemsetAsync(gcoarse, 0, 256 * 4, stream);

  prep_kernel<<<NS_BLK + CB4 + 2 * WKB + FB4, 256, 0, stream>>>(
      ei, et, gcoarse, x, xb, basis1, root1, WT1, basis2, root2, WT2, packed);
  coarse_prefix_kernel<<<1, 256, 0, stream>>>(gcoarse, gbase, gcur);
  coarse_scatter_kernel<<<NS_BLK, 256, 0, stream>>>(ei, et, gcur, coarse);
  fine_hist_kernel<<<NHI, 256, 0, stream>>>(coarse, gbase, gcoarse,
                                            comp1, wtab1, comp2, wtab2,
                                            lestart, btot);
  btot_prefix_kernel<<<1, 256, 0, stream>>>(btot, bbase, estart);
  fine_scatter_kernel<<<NHI, 256, 0, stream>>>(coarse, gbase, gcoarse, bbase,
                                               lestart, estart, packed);

  dim3 ggrid((N_NODES + BM - 1) / BM, 1);  // 391 blocks, full N per block
  const int AB = (N_NODES + 3) / 4;        // 12500 blocks, wave per node

  // Layer 1
  aggregate_kernel<<<AB, 256, 0, stream>>>(xb, packed, estart, wtab1, zA);
  gemm_kernel<true, __hip_bfloat16><<<ggrid, 512, 0, stream>>>(
      zA, (const __hip_bfloat16*)xb, WT1, bias1, h, N_NODES);

  // Layer 2 (h is bf16 [N][256] — same packed-uint view as xb)
  aggregate_kernel<<<AB, 256, 0, stream>>>((const unsigned*)h, packed, estart,
                                           wtab2, zA);
  gemm_kernel<false, float><<<ggrid, 512, 0, stream>>>(
      zA, h, WT2, bias2, out, N_NODES);
}

// Round 8
// 431.909 us; speedup vs baseline: 1.0840x; 1.0226x over previous
//
#include <hip/hip_runtime.h>
#include <hip/hip_bf16.h>

// Problem constants (fixed by the reference)
constexpr int N_NODES = 50000;
constexpr int N_EDGES = 800000;
constexpr int R_REL   = 8;
constexpr int BASES   = 4;
constexpr int D       = 256;                 // DIN = DH = DOUT
constexpr int KZ      = BASES * D;           // 1024: basis-space aggregate
constexpr int KT      = KZ + D;              // 1280: + self block
constexpr int WSTRIDE = 16;                  // wtab float4s per node (slots 8..15
                                             // are zero -> dummy edges)
constexpr int DUMMY_P = 8 << 20;             // dummy edge: src=0, rel=8

// Sort geometry (round 8): bucket = 128 consecutive dst nodes; fully
// deterministic two-level counting sort -- ZERO global atomics (R4 showed
// device-scope atomics cap at ~9.6G/s; even P1's 39K flush atomics cost us).
constexpr int BUCK   = 128;                     // nodes per coarse bucket
constexpr int NHI    = (N_NODES + BUCK - 1) / BUCK;  // 391 buckets
constexpr int NS_BLK = 400;                     // coarse-pass blocks
constexpr int CH     = N_EDGES / NS_BLK;        // 2000 edges/block (exact)

// grid geometry
constexpr int CB4 = (N_NODES * 128) / 1024;       // 6250 (exact; 4 uints/thread)
constexpr int WKB = KT / 64;                      // 20 (make_w blocks per layer)
constexpr int CAP = N_EDGES + N_NODES * 8;        // 1,200,000 padded edge cap
constexpr int FB4 = (CAP + 1023) / 1024;          // 1172 (4 ints/thread)

typedef __attribute__((ext_vector_type(8))) short bf16x8;
typedef __attribute__((ext_vector_type(4))) float f32x4;

__device__ inline float bfu_lo(unsigned u) { return __uint_as_float(u << 16); }
__device__ inline float bfu_hi(unsigned u) { return __uint_as_float(u & 0xFFFF0000u); }
__device__ inline unsigned short f2bu(float f) {
  __hip_bfloat16 h = __float2bfloat16(f);
  return *reinterpret_cast<unsigned short*>(&h);
}
__device__ inline void store_out(float* p, float v) { *p = v; }
__device__ inline void store_out(__hip_bfloat16* p, float v) { *p = __float2bfloat16(v); }

// async 16B global -> LDS (wave-uniform lds base + lane*16)
__device__ inline void gload_lds16(void* lds, const void* g) {
  __builtin_amdgcn_global_load_lds(
      (const __attribute__((address_space(1))) unsigned*)g,
      (__attribute__((address_space(3))) unsigned*)lds, 16, 0, 0);
}

// in-block scan helpers -----------------------------------------------------
// inclusive Hillis-Steele over sd[0..511], 256 threads x 2 elements.
// Reads happen before the mid-sync, writes after -> race-free.
__device__ inline void scan512(int* sd, int tid) {
  for (int off = 1; off < 512; off <<= 1) {
    int a = (tid >= off) ? sd[tid - off] : 0;
    int b = (tid + 256 >= off) ? sd[tid + 256 - off] : 0;
    __syncthreads();
    sd[tid] += a;
    sd[tid + 256] += b;
    __syncthreads();
  }
}

// ---------------------------------------------------------------------------
// 1. Fused prep: [P1 per-block bucket hist (plain stores, no atomics) |
//    convert x->bf16 | make_w x2 | dummy-fill packed]
// ---------------------------------------------------------------------------
__global__ __launch_bounds__(256) void prep_kernel(
    const int* __restrict__ ei,
    int* __restrict__ ghist,               // [NHI][NS_BLK]
    const float* __restrict__ x, unsigned* __restrict__ x2,
    const float* __restrict__ basis1, const float* __restrict__ root1,
    __hip_bfloat16* __restrict__ WT1,
    const float* __restrict__ basis2, const float* __restrict__ root2,
    __hip_bfloat16* __restrict__ WT2,
    int* __restrict__ packed) {
  __shared__ __hip_bfloat16 tile[16][256];   // 8 KB (make_w)
  __shared__ int hist[NHI];                  // (P1)
  int bid = blockIdx.x;
  int tid = threadIdx.x;

  if (bid < NS_BLK) {                   // --- P1: per-block bucket histogram ---
    for (int k = tid; k < NHI; k += 256) hist[k] = 0;
    __syncthreads();
    int start = bid * CH;
    for (int i = start + tid; i < start + CH; i += 256)
      atomicAdd(&hist[ei[N_EDGES + i] >> 7], 1);   // LDS atomic only
    __syncthreads();
    for (int k = tid; k < NHI; k += 256)
      ghist[(size_t)k * NS_BLK + bid] = hist[k];   // plain store
    return;
  }
  bid -= NS_BLK;
  if (bid < CB4) {                      // --- convert x -> bf16 (4 uints/thr) ---
    int idx = (bid * 256 + tid) * 4;    // exact: CB4*1024 == N*128
    const float* px = x + (size_t)idx * 2;
    float4 a = *(const float4*)(px);
    float4 b = *(const float4*)(px + 4);
    uint4 o;
    o.x = (unsigned)f2bu(a.x) | ((unsigned)f2bu(a.y) << 16);
    o.y = (unsigned)f2bu(a.z) | ((unsigned)f2bu(a.w) << 16);
    o.z = (unsigned)f2bu(b.x) | ((unsigned)f2bu(b.y) << 16);
    o.w = (unsigned)f2bu(b.z) | ((unsigned)f2bu(b.w) << 16);
    *(uint4*)(x2 + idx) = o;
    return;
  }
  bid -= CB4;
  if (bid < 2 * WKB) {                  // --- weight build (both layers) ---
    const float* basis = (bid < WKB) ? basis1 : basis2;
    const float* root  = (bid < WKB) ? root1 : root2;
    __hip_bfloat16* WT = (bid < WKB) ? WT1 : WT2;
    int wb = (bid < WKB) ? bid : bid - WKB;
    int k0 = wb * 64;
#pragma unroll
    for (int pass = 0; pass < 4; pass++) {
      int kp = k0 + pass * 16;
#pragma unroll
      for (int r = 0; r < 16; r++) {
        int k = kp + r;
        const float* srow = (k < KZ)
            ? basis + ((size_t)(k & 3) * D + (k >> 2)) * D
            : root + (size_t)(k - KZ) * D;
        tile[r][tid] = __float2bfloat16(srow[tid]);
      }
      __syncthreads();
      __hip_bfloat16* dst = WT + (size_t)tid * KT + kp;
#pragma unroll
      for (int c = 0; c < 2; c++) {
        union { short s[8]; int4 v; } u;
#pragma unroll
        for (int r = 0; r < 8; r++)
          u.s[r] = *reinterpret_cast<short*>(&tile[c * 8 + r][tid]);
        *(int4*)(dst + c * 8) = u.v;
      }
      __syncthreads();
    }
    return;
  }
  bid -= 2 * WKB;
  {                                     // --- dummy-fill packed (4 ints/thr) ---
    int i = (bid * 256 + tid) * 4;
    if (i < CAP) {                      // CAP % 4 == 0 -> full int4 valid
      int4 f = make_int4(DUMMY_P, DUMMY_P, DUMMY_P, DUMMY_P);
      *(int4*)(packed + i) = f;
    }
  }
}

// ---------------------------------------------------------------------------
// 2. binprefix: per bucket, exclusive prefix of ghist[b][*] over the 400
//    coarse blocks -> boffs; bintot[b] = bucket edge count.
// ---------------------------------------------------------------------------
__global__ __launch_bounds__(256) void binprefix_kernel(
    const int* __restrict__ ghist, int* __restrict__ boffs,
    int* __restrict__ bintot) {
  __shared__ int sd[512];
  int b = blockIdx.x;
  int tid = threadIdx.x;
  int v0 = (tid < NS_BLK) ? ghist[(size_t)b * NS_BLK + tid] : 0;
  int v1 = (tid + 256 < NS_BLK) ? ghist[(size_t)b * NS_BLK + tid + 256] : 0;
  sd[tid] = v0;
  sd[tid + 256] = v1;
  __syncthreads();
  scan512(sd, tid);
  if (tid < NS_BLK) boffs[(size_t)b * NS_BLK + tid] = sd[tid] - v0;
  if (tid + 256 < NS_BLK)
    boffs[(size_t)b * NS_BLK + tid + 256] = sd[tid + 256] - v1;
  if (tid == 255) bintot[b] = sd[511];
}

// ---------------------------------------------------------------------------
// 3. coarse scatter (400 blocks, no global atomics): position =
//    scan(bintot)[bin] + boffs[bin][blk] + LDS rank. Word:
//    src[15:0] | rt[18:16] | dstlo[25:19].
// ---------------------------------------------------------------------------
__global__ __launch_bounds__(256) void coarse_scatter_kernel(
    const int* __restrict__ ei, const int* __restrict__ et,
    const int* __restrict__ bintot, const int* __restrict__ boffs,
    int* __restrict__ coarse) {
  __shared__ int lbase[NHI];
  __shared__ int lcnt[NHI];
  __shared__ int sd[512];
  int bid = blockIdx.x;
  int tid = threadIdx.x;
  for (int k = tid; k < NHI; k += 256) lcnt[k] = 0;
  int v0 = (tid < NHI) ? bintot[tid] : 0;
  int v1 = (tid + 256 < NHI) ? bintot[tid + 256] : 0;
  sd[tid] = v0;
  sd[tid + 256] = v1;
  __syncthreads();
  scan512(sd, tid);
  if (tid < NHI) lbase[tid] = (sd[tid] - v0) + boffs[(size_t)tid * NS_BLK + bid];
  if (tid + 256 < NHI)
    lbase[tid + 256] =
        (sd[tid + 256] - v1) + boffs[(size_t)(tid + 256) * NS_BLK + bid];
  __syncthreads();
  int start = bid * CH;
  for (int i = start + tid; i < start + CH; i += 256) {
    int src = ei[i];
    int dst = ei[N_EDGES + i];
    int rt  = et[i];
    int bin = dst >> 7;
    int rank = atomicAdd(&lcnt[bin], 1);   // LDS atomic
    coarse[lbase[bin] + rank] = src | (rt << 16) | ((dst & 127) << 19);
  }
}

// ---------------------------------------------------------------------------
// 4. fine_hist (391 blocks): fine hist over 128x8 keys; wtab1/2 built from
//    the in-LDS histogram; padded per-node local prefix + bucket total.
// ---------------------------------------------------------------------------
__global__ __launch_bounds__(256) void fine_hist_kernel(
    const int* __restrict__ coarse, const int* __restrict__ bintot,
    const float* __restrict__ comp1, float4* __restrict__ wtab1,
    const float* __restrict__ comp2, float4* __restrict__ wtab2,
    int* __restrict__ lestart, int* __restrict__ btot) {
  __shared__ int c2[BUCK * R_REL];   // 4 KB fine histogram
  __shared__ int sd[512];
  int b = blockIdx.x;
  int tid = threadIdx.x;
#pragma unroll
  for (int k = tid; k < BUCK * R_REL; k += 256) c2[k] = 0;
  // cbase = exclusive scan of bintot at b
  int v0 = (tid < NHI) ? bintot[tid] : 0;
  int v1 = (tid + 256 < NHI) ? bintot[tid + 256] : 0;
  sd[tid] = v0;
  sd[tid + 256] = v1;
  __syncthreads();
  scan512(sd, tid);
  int n_e = bintot[b];
  int cbase = sd[b] - n_e;
  __syncthreads();
  for (int i = tid; i < n_e; i += 256) {
    int e = coarse[cbase + i];
    int key = ((e >> 19) & 127) * R_REL + ((e >> 16) & 7);
    atomicAdd(&c2[key], 1);            // LDS atomic
  }
  __syncthreads();
  // winv (both layers) straight from the LDS histogram
  int nodebase = b * BUCK;
  for (int k = tid; k < BUCK * WSTRIDE; k += 256) {
    int lo = k >> 4, r = k & (WSTRIDE - 1);
    int n = nodebase + lo;
    if (n < N_NODES) {
      float4 w1 = make_float4(0.f, 0.f, 0.f, 0.f);
      float4 w2 = w1;
      if (r < R_REL) {
        int c = c2[lo * R_REL + r];
        float inv = 1.0f / (float)(c > 0 ? c : 1);
        w1.x = comp1[r * BASES + 0] * inv;
        w1.y = comp1[r * BASES + 1] * inv;
        w1.z = comp1[r * BASES + 2] * inv;
        w1.w = comp1[r * BASES + 3] * inv;
        w2.x = comp2[r * BASES + 0] * inv;
        w2.y = comp2[r * BASES + 1] * inv;
        w2.z = comp2[r * BASES + 2] * inv;
        w2.w = comp2[r * BASES + 3] * inv;
      }
      wtab1[(size_t)n * WSTRIDE + r] = w1;
      wtab2[(size_t)n * WSTRIDE + r] = w2;
    }
  }
  // padded degree + local prefix (thread tid<BUCK owns node nodebase+tid)
  int d = 0;
  if (tid < BUCK) {
#pragma unroll
    for (int r = 0; r < R_REL; r++) d += c2[tid * R_REL + r];
  }
  int dp = (d + 7) & ~7;
  __syncthreads();                     // c2 reads done; sd reuse below
  sd[tid] = dp;
  __syncthreads();
  for (int off = 1; off < 256; off <<= 1) {
    int t = (tid >= off) ? sd[tid - off] : 0;
    __syncthreads();
    sd[tid] += t;
    __syncthreads();
  }
  if (tid < BUCK) lestart[b * BUCK + tid] = sd[tid] - dp;
  if (tid == 255) btot[b] = sd[255];
}

// ---------------------------------------------------------------------------
// 5. fine_scatter (391 blocks): bbase/cbase re-derived in-block; writes
//    estart and the final padded packed layout (pads keep DUMMY_P).
// ---------------------------------------------------------------------------
__global__ __launch_bounds__(256) void fine_scatter_kernel(
    const int* __restrict__ coarse, const int* __restrict__ bintot,
    const int* __restrict__ btot, const int* __restrict__ lestart,
    int* __restrict__ estart, int* __restrict__ packed) {
  __shared__ int lest[BUCK];
  __shared__ int lcur[BUCK];
  __shared__ int sd[512];
  int b = blockIdx.x;
  int tid = threadIdx.x;
  if (tid < BUCK) {
    lest[tid] = lestart[b * BUCK + tid];
    lcur[tid] = 0;
  }
  // cbase from bintot scan
  int v0 = (tid < NHI) ? bintot[tid] : 0;
  int v1 = (tid + 256 < NHI) ? bintot[tid + 256] : 0;
  sd[tid] = v0;
  sd[tid + 256] = v1;
  __syncthreads();
  scan512(sd, tid);
  int n_e = bintot[b];
  int cbase = sd[b] - n_e;
  __syncthreads();
  // bbase from btot scan
  int w0 = (tid < NHI) ? btot[tid] : 0;
  int w1 = (tid + 256 < NHI) ? btot[tid + 256] : 0;
  sd[tid] = w0;
  sd[tid + 256] = w1;
  __syncthreads();
  scan512(sd, tid);
  int bt = btot[b];
  int bb = sd[b] - bt;
  __syncthreads();
  {
    int n = b * BUCK + tid;
    if (tid < BUCK && n < N_NODES) estart[n] = bb + lest[tid];
    if (b == NHI - 1 && tid == 0) estart[N_NODES] = bb + bt;
  }
  __syncthreads();
  for (int i = tid; i < n_e; i += 256) {
    int e = coarse[cbase + i];
    int lo = (e >> 19) & 127;
    int rank = atomicAdd(&lcur[lo], 1);   // LDS atomic
    packed[bb + lest[lo] + rank] = (e & 0xFFFF) | (((e >> 16) & 7) << 20);
  }
}

// ---------------------------------------------------------------------------
// 6. Aggregate into basis space. WAVE per node (4/block). All wave-uniform
//    work (edge list, weights, row bases) on the SCALAR pipe via
//    readfirstlane; buckets padded to x8 -> branch/mask-free inner loop.
//    At its transport floor: FETCH ~191MB = 8 XCDs x 25.6MB compulsory x2
//    reads (random src), WRITE 100MB = zA; 291MB/67.5us ~ 4.3 TB/s.
// ---------------------------------------------------------------------------
__device__ inline float2 pfma(float s, float2 a, float2 c) {
  c.x = fmaf(s, a.x, c.x);
  c.y = fmaf(s, a.y, c.y);
  return c;
}

__device__ inline void edge_fma(float2 acc[BASES][2], uint2 v, float4 w) {
  float2 a01 = make_float2(bfu_lo(v.x), bfu_hi(v.x));
  float2 a23 = make_float2(bfu_lo(v.y), bfu_hi(v.y));
  acc[0][0] = pfma(w.x, a01, acc[0][0]); acc[0][1] = pfma(w.x, a23, acc[0][1]);
  acc[1][0] = pfma(w.y, a01, acc[1][0]); acc[1][1] = pfma(w.y, a23, acc[1][1]);
  acc[2][0] = pfma(w.z, a01, acc[2][0]); acc[2][1] = pfma(w.z, a23, acc[2][1]);
  acc[3][0] = pfma(w.w, a01, acc[3][0]); acc[3][1] = pfma(w.w, a23, acc[3][1]);
}

__global__ __launch_bounds__(256) void aggregate_kernel(
    const unsigned* __restrict__ x2,   // bf16 features as uint pairs [N][128]
    const int* __restrict__ packed,    // padded-x8 buckets
    const int* __restrict__ estart,    // padded offsets
    const float4* __restrict__ wtab,   // [N*16]; slots 8..15 zero (dummy)
    __hip_bfloat16* __restrict__ zA)   // [N][KZ]
{
  int tid = threadIdx.x;
  int lane = tid & 63;
  int n = __builtin_amdgcn_readfirstlane(blockIdx.x * 4 + (tid >> 6));
  int s = __builtin_amdgcn_readfirstlane(estart[n]);
  int e = __builtin_amdgcn_readfirstlane(estart[n + 1]);
  const int voff = lane * 2;                         // uint index within row
  const float4* wt = wtab + (size_t)n * WSTRIDE;

  float2 acc[BASES][2] = {};

  for (int base = s; base < e; base += 8) {
    int4 q0 = *(const int4*)(packed + base);         // uniform addr -> s_load
    int4 q1 = *(const int4*)(packed + base + 4);
    int p0 = __builtin_amdgcn_readfirstlane(q0.x);
    int p1 = __builtin_amdgcn_readfirstlane(q0.y);
    int p2 = __builtin_amdgcn_readfirstlane(q0.z);
    int p3 = __builtin_amdgcn_readfirstlane(q0.w);
    int p4 = __builtin_amdgcn_readfirstlane(q1.x);
    int p5 = __builtin_amdgcn_readfirstlane(q1.y);
    int p6 = __builtin_amdgcn_readfirstlane(q1.z);
    int p7 = __builtin_amdgcn_readfirstlane(q1.w);
    // SGPR row bases; vector part is just base+voff
    const unsigned* r0 = x2 + ((size_t)(p0 & 0xFFFFF) << 7);
    const unsigned* r1 = x2 + ((size_t)(p1 & 0xFFFFF) << 7);
    const unsigned* r2 = x2 + ((size_t)(p2 & 0xFFFFF) << 7);
    const unsigned* r3 = x2 + ((size_t)(p3 & 0xFFFFF) << 7);
    const unsigned* r4 = x2 + ((size_t)(p4 & 0xFFFFF) << 7);
    const unsigned* r5 = x2 + ((size_t)(p5 & 0xFFFFF) << 7);
    const unsigned* r6 = x2 + ((size_t)(p6 & 0xFFFFF) << 7);
    const unsigned* r7 = x2 + ((size_t)(p7 & 0xFFFFF) << 7);
    uint2 v0 = *(const uint2*)(r0 + voff);
    uint2 v1 = *(const uint2*)(r1 + voff);
    uint2 v2 = *(const uint2*)(r2 + voff);
    uint2 v3 = *(const uint2*)(r3 + voff);
    uint2 v4 = *(const uint2*)(r4 + voff);
    uint2 v5 = *(const uint2*)(r5 + voff);
    uint2 v6 = *(const uint2*)(r6 + voff);
    uint2 v7 = *(const uint2*)(r7 + voff);
    float4 w0 = wt[p0 >> 20];                        // uniform -> s_load_x4
    float4 w1 = wt[p1 >> 20];
    float4 w2 = wt[p2 >> 20];
    float4 w3 = wt[p3 >> 20];
    float4 w4 = wt[p4 >> 20];
    float4 w5 = wt[p5 >> 20];
    float4 w6 = wt[p6 >> 20];
    float4 w7 = wt[p7 >> 20];
    edge_fma(acc, v0, w0);
    edge_fma(acc, v1, w1);
    edge_fma(acc, v2, w2);
    edge_fma(acc, v3, w3);
    edge_fma(acc, v4, w4);
    edge_fma(acc, v5, w5);
    edge_fma(acc, v6, w6);
    edge_fma(acc, v7, w7);
  }

  // store: k = (4*lane+j)*4 + b = 16*lane + 4*j + b -> 32 contiguous bytes
  union { short s[8]; int4 v; } u0, u1;
#pragma unroll
  for (int b = 0; b < BASES; b++) {
    u0.s[b]     = (short)f2bu(acc[b][0].x);
    u0.s[4 + b] = (short)f2bu(acc[b][0].y);
    u1.s[b]     = (short)f2bu(acc[b][1].x);
    u1.s[4 + b] = (short)f2bu(acc[b][1].y);
  }
  __hip_bfloat16* zrow = zA + (size_t)n * KZ;
  *(int4*)(zrow + 16 * lane) = u0.v;
  *(int4*)(zrow + 16 * lane + 8) = u1.v;
}

// ---------------------------------------------------------------------------
// 7. GEMM: C[M,256] = A[M,1280](bf16) @ WT^T + bias. BM=128, BN=256, 512
//    threads / 8 waves, BK=32. 2-phase double-buffered staging: raw
//    s_barrier + counted vmcnt(3) keeps next tile's loads in flight while
//    MFMA runs. A split: k<1024 from Az, k>=1024 from Aself (xb/h).
// ---------------------------------------------------------------------------
#define BM 128
#define BN 256
#define BK 32

template <bool RELU, typename OutT>
__global__ __launch_bounds__(512) void gemm_kernel(
    const __hip_bfloat16* __restrict__ Az,     // [M, KZ]
    const __hip_bfloat16* __restrict__ Aself,  // [M, D]
    const __hip_bfloat16* __restrict__ Bt,     // [256, KT]
    const float* __restrict__ bias, OutT* __restrict__ C, int M) {
  __shared__ __align__(16) __hip_bfloat16 As[2][BM * BK];  // 2 x 8 KB
  __shared__ __align__(16) __hip_bfloat16 Bs[2][BN * BK];  // 2 x 16 KB
  int tid = threadIdx.x;
  int m0 = blockIdx.x * BM;
  int wave = tid >> 6, lane = tid & 63;
  int wm = wave & 1, wn = wave >> 1;   // 2 x 4 wave grid, 64x64 tiles
  int l15 = lane & 15, quad = lane >> 4;

  int colS = (lane & 3) * 8;
  int rowA = wave * 16 + (lane >> 2);           // 0..127 across 8 waves
  int grA  = min(m0 + rowA, M - 1);             // clamp; epilogue masks tail
  const __hip_bfloat16* gAz = Az + (size_t)grA * KZ + colS;
  const __hip_bfloat16* gAs = Aself + (size_t)grA * D + colS;
  const __hip_bfloat16* gB0 = Bt + (size_t)(wave * 32 + (lane >> 2)) * KT + colS;
  const __hip_bfloat16* gB1 = gB0 + 16 * KT;

  f32x4 acc[4][4] = {};

  auto stage = [&](int buf, int k0) {
    const __hip_bfloat16* srcA = (k0 < KZ) ? (gAz + k0) : (gAs + (k0 - KZ));
    gload_lds16(As[buf] + wave * 512, srcA);
    gload_lds16(Bs[buf] + wave * 1024, gB0 + k0);
    gload_lds16(Bs[buf] + wave * 1024 + 512, gB1 + k0);
  };

  stage(0, 0);
  int cur = 0;
  for (int k0 = 0; k0 < KT; k0 += BK) {
    if (k0 + BK < KT) {
      stage(cur ^ 1, k0 + BK);                      // prefetch next tile
      asm volatile("s_waitcnt vmcnt(3)" ::: "memory");  // cur's 3 loads done
    } else {
      asm volatile("s_waitcnt vmcnt(0)" ::: "memory");  // tail: drain all
    }
    __builtin_amdgcn_s_barrier();
    __builtin_amdgcn_sched_barrier(0);

    bf16x8 af[4], bfr[4];
#pragma unroll
    for (int mt = 0; mt < 4; mt++)
      af[mt] = *(const bf16x8*)(As[cur] + (wm * 64 + mt * 16 + l15) * BK + quad * 8);
#pragma unroll
    for (int nt = 0; nt < 4; nt++)
      bfr[nt] = *(const bf16x8*)(Bs[cur] + (wn * 64 + nt * 16 + l15) * BK + quad * 8);
#pragma unroll
    for (int mt = 0; mt < 4; mt++)
#pragma unroll
      for (int nt = 0; nt < 4; nt++)
        acc[mt][nt] = __builtin_amdgcn_mfma_f32_16x16x32_bf16(
            af[mt], bfr[nt], acc[mt][nt], 0, 0, 0);
    __builtin_amdgcn_s_barrier();   // all reads of buf cur retired
    cur ^= 1;
  }

  // epilogue: C/D layout col = lane&15, row = quad*4 + reg
#pragma unroll
  for (int nt = 0; nt < 4; nt++) {
    int cg = wn * 64 + nt * 16 + l15;
    float bv = bias[cg];
#pragma unroll
    for (int mt = 0; mt < 4; mt++) {
#pragma unroll
      for (int r = 0; r < 4; r++) {
        int rg = m0 + wm * 64 + mt * 16 + quad * 4 + r;
        if (rg < M) {
          float v = acc[mt][nt][r] + bv;
          if (RELU) v = fmaxf(v, 0.f);
          store_out(C + (size_t)rg * D + cg, v);
        }
      }
    }
  }
}

// ---------------------------------------------------------------------------
// Launch (9 dispatches, no memsets, no global atomics anywhere)
// ---------------------------------------------------------------------------
static inline char* carve(char*& p, size_t bytes) {
  char* r = p;
  p += (bytes + 255) & ~(size_t)255;
  return r;
}

extern "C" void kernel_launch(void* const* d_in, const int* in_sizes, int n_in,
                              void* d_out, int out_size, void* d_ws,
                              size_t ws_size, hipStream_t stream) {
  const float* x      = (const float*)d_in[0];
  const int*   ei     = (const int*)d_in[1];
  const int*   et     = (const int*)d_in[2];
  const float* basis1 = (const float*)d_in[3];
  const float* comp1  = (const float*)d_in[4];
  const float* root1  = (const float*)d_in[5];
  const float* bias1  = (const float*)d_in[6];
  const float* basis2 = (const float*)d_in[7];
  const float* comp2  = (const float*)d_in[8];
  const float* root2  = (const float*)d_in[9];
  const float* bias2  = (const float*)d_in[10];
  float* out = (float*)d_out;

  char* ws = (char*)d_ws;
  int* estart  = (int*)carve(ws, (size_t)(N_NODES + 1) * 4);
  int* coarse  = (int*)carve(ws, (size_t)N_EDGES * 4);
  int* ghist   = (int*)carve(ws, (size_t)NHI * NS_BLK * 4);
  int* boffs   = (int*)carve(ws, (size_t)NHI * NS_BLK * 4);
  int* bintot  = (int*)carve(ws, 512 * 4);
  int* btot    = (int*)carve(ws, 512 * 4);
  int* lestart = (int*)carve(ws, (size_t)NHI * BUCK * 4);
  int* packed  = (int*)carve(ws, (size_t)CAP * 4);
  float4* wtab1 = (float4*)carve(ws, (size_t)N_NODES * WSTRIDE * 16);
  float4* wtab2 = (float4*)carve(ws, (size_t)N_NODES * WSTRIDE * 16);
  __hip_bfloat16* WT1 = (__hip_bfloat16*)carve(ws, (size_t)D * KT * 2);
  __hip_bfloat16* WT2 = (__hip_bfloat16*)carve(ws, (size_t)D * KT * 2);
  unsigned* xb = (unsigned*)carve(ws, (size_t)N_NODES * D * 2);   // bf16 x
  __hip_bfloat16* h = (__hip_bfloat16*)carve(ws, (size_t)N_NODES * D * 2);
  __hip_bfloat16* zA = (__hip_bfloat16*)carve(ws, (size_t)N_NODES * KZ * 2);

  prep_kernel<<<NS_BLK + CB4 + 2 * WKB + FB4, 256, 0, stream>>>(
      ei, ghist, x, xb, basis1, root1, WT1, basis2, root2, WT2, packed);
  binprefix_kernel<<<NHI, 256, 0, stream>>>(ghist, boffs, bintot);
  coarse_scatter_kernel<<<NS_BLK, 256, 0, stream>>>(ei, et, bintot, boffs,
                                                    coarse);
  fine_hist_kernel<<<NHI, 256, 0, stream>>>(coarse, bintot, comp1, wtab1,
                                            comp2, wtab2, lestart, btot);
  fine_scatter_kernel<<<NHI, 256, 0, stream>>>(coarse, bintot, btot, lestart,
                                               estart, packed);

  dim3 ggrid((N_NODES + BM - 1) / BM, 1);  // 391 blocks, full N per block
  const int AB = (N_NODES + 3) / 4;        // 12500 blocks, wave per node

  // Layer 1
  aggregate_kernel<<<AB, 256, 0, stream>>>(xb, packed, estart, wtab1, zA);
  gemm_kernel<true, __hip_bfloat16><<<ggrid, 512, 0, stream>>>(
      zA, (const __hip_bfloat16*)xb, WT1, bias1, h, N_NODES);

  // Layer 2 (h is bf16 [N][256] — same packed-uint view as xb)
  aggregate_kernel<<<AB, 256, 0, stream>>>((const unsigned*)h, packed, estart,
                                           wtab2, zA);
  gemm_kernel<false, float><<<ggrid, 512, 0, stream>>>(
      zA, h, WT2, bias2, out, N_NODES);
}